// Round 3
// 8001.363 us; speedup vs baseline: 1.0628x; 1.0628x over previous
//
#include <hip/hip_runtime.h>
#include <math.h>

// ---------------- problem constants ----------------
#define TS   2048   // timesteps
#define NN   100    // nodes
#define FD   128    // input features
#define HD   512    // hidden
#define G3   1536   // 3*HD
#define NG   7      // node groups of 16
#define NSL  8      // hidden slices (64 h-cols each)
#define KNN  8
#define GIN  704    // HD + 64 + 128
#define GH   256
#define GOUT 128

typedef float  f32x4  __attribute__((ext_vector_type(4)));
typedef __bf16 bf16x8 __attribute__((ext_vector_type(8)));
#define MFMA16(a, b, c) __builtin_amdgcn_mfma_f32_16x16x32_bf16((a), (b), (c), 0, 0, 0)

#define WXST 136   // Wx/Ax LDS row stride (bf16): 272B, 16B-aligned

__device__ __forceinline__ float sig_(float v) {
    return __builtin_amdgcn_rcpf(1.f + __expf(-v));
}
__device__ __forceinline__ float tanh_(float v) {
    float e = __expf(2.f * v);
    return 1.f - 2.f * __builtin_amdgcn_rcpf(e + 1.f);   // saturates at +/-1
}

// ---------- agent-scope memory helpers (sc0 sc1: coherent at LLC) ----------
// All cross-block h/tag traffic goes through the LLC. Placement-independent,
// no assumptions about workgroup->XCD mapping. This is the protocol that has
// passed verification on hardware (round 0); the XCD-local sc0 variant is
// retired until it can be brought up safely.

__device__ __forceinline__ void loadh8_lo(const __bf16* base, unsigned voff, f32x4* h) {
    asm volatile(
        "global_load_dwordx4 %0, %8, %9 sc0 sc1\n\t"
        "global_load_dwordx4 %1, %8, %9 offset:64 sc0 sc1\n\t"
        "global_load_dwordx4 %2, %8, %9 offset:128 sc0 sc1\n\t"
        "global_load_dwordx4 %3, %8, %9 offset:192 sc0 sc1\n\t"
        "global_load_dwordx4 %4, %8, %9 offset:256 sc0 sc1\n\t"
        "global_load_dwordx4 %5, %8, %9 offset:320 sc0 sc1\n\t"
        "global_load_dwordx4 %6, %8, %9 offset:384 sc0 sc1\n\t"
        "global_load_dwordx4 %7, %8, %9 offset:448 sc0 sc1\n\t"
        "s_waitcnt vmcnt(0)"
        : "=&v"(h[0]), "=&v"(h[1]), "=&v"(h[2]), "=&v"(h[3]),
          "=&v"(h[4]), "=&v"(h[5]), "=&v"(h[6]), "=&v"(h[7])
        : "v"(voff), "s"(base) : "memory");
}
__device__ __forceinline__ void loadh8_hi(const __bf16* base, unsigned voff, f32x4* h) {
    asm volatile(
        "global_load_dwordx4 %0, %8, %9 offset:512 sc0 sc1\n\t"
        "global_load_dwordx4 %1, %8, %9 offset:576 sc0 sc1\n\t"
        "global_load_dwordx4 %2, %8, %9 offset:640 sc0 sc1\n\t"
        "global_load_dwordx4 %3, %8, %9 offset:704 sc0 sc1\n\t"
        "global_load_dwordx4 %4, %8, %9 offset:768 sc0 sc1\n\t"
        "global_load_dwordx4 %5, %8, %9 offset:832 sc0 sc1\n\t"
        "global_load_dwordx4 %6, %8, %9 offset:896 sc0 sc1\n\t"
        "global_load_dwordx4 %7, %8, %9 offset:960 sc0 sc1\n\t"
        "s_waitcnt vmcnt(0)"
        : "=&v"(h[0]), "=&v"(h[1]), "=&v"(h[2]), "=&v"(h[3]),
          "=&v"(h[4]), "=&v"(h[5]), "=&v"(h[6]), "=&v"(h[7])
        : "v"(voff), "s"(base) : "memory");
}

__device__ __forceinline__ void storeh4_a(__bf16* base, unsigned voff,
                                          unsigned v0, unsigned v1, unsigned v2, unsigned v3) {
    asm volatile(
        "global_store_short %4, %0, %5 sc0 sc1\n\t"
        "global_store_short %4, %1, %5 offset:1024 sc0 sc1\n\t"
        "global_store_short %4, %2, %5 offset:2048 sc0 sc1\n\t"
        "global_store_short %4, %3, %5 offset:3072 sc0 sc1"
        :: "v"(v0), "v"(v1), "v"(v2), "v"(v3), "v"(voff), "s"(base) : "memory");
}

__device__ __forceinline__ void tagstore_a(int* base, unsigned voff, int val) {
    asm volatile("global_store_dword %1, %0, %2 sc0 sc1" :: "v"(val), "v"(voff), "s"(base) : "memory");
}
__device__ __forceinline__ int tagload_a(const int* base, unsigned voff) {
    int v;
    asm volatile("global_load_dword %0, %1, %2 sc0 sc1\n\ts_waitcnt vmcnt(0)"
                 : "=v"(v) : "v"(voff), "s"(base) : "memory");
    return v;
}

__device__ __forceinline__ bf16x8 cvt8(const float* p) {
    float4 a = *(const float4*)p, b = *(const float4*)(p + 4);
    bf16x8 r;
    r[0] = (__bf16)a.x; r[1] = (__bf16)a.y; r[2] = (__bf16)a.z; r[3] = (__bf16)a.w;
    r[4] = (__bf16)b.x; r[5] = (__bf16)b.y; r[6] = (__bf16)b.z; r[7] = (__bf16)b.w;
    return r;
}

// =====================================================================
// Persistent GRU main loop. 56 blocks x 256 threads (4 waves).
// block (g,s): nodes [16g,16g+16), h-cols [64s,64s+64); wave w: 16 cols.
// Whh B-frags (48 = 192 regs) in registers; Wih in LDS; hold in regs.
// All cross-block exchange via LLC (sc0 sc1) -- placement-independent.
//
// Split-poll pipelined consume: proceed when producers 0-3 are ready,
// load+compute their h-slices while producers 4-7 settle (readiness
// bitmap from the same wave-parallel tag poll is cached, so the second
// check costs zero extra loads in the common all-ready case).
// =====================================================================
__device__ void gru_loop(const float* __restrict__ x,
                         const float* __restrict__ Wih, const float* __restrict__ Whh,
                         const float* __restrict__ bih, const float* __restrict__ bhh,
                         __bf16* h0buf, __bf16* h1buf, float* enc, int* tags,
                         int g, int s, __bf16* WxP, __bf16* AxP)
{
    const int tid = threadIdx.x;
    const int w   = tid >> 6;
    const int ln  = tid & 63;
    const int nb  = g * 16;
    const int mi  = ln & 15;
    const int kq8 = (ln >> 4) * 8;
    const int cl  = 16 * w + mi;
    const int ch  = 64 * s + cl;

    // ---- one-time: Wih slice -> LDS (192 gate rows x 128 K) ----
    for (int idx = tid; idx < 192 * 32; idx += 256) {
        int row = idx >> 5, c4 = idx & 31;
        int grow = (row >> 6) * HD + 64 * s + (row & 63);
        float4 v = ((const float4*)(Wih + (size_t)grow * FD))[c4];
        __bf16* d = WxP + row * WXST + c4 * 4;
        d[0] = (__bf16)v.x; d[1] = (__bf16)v.y; d[2] = (__bf16)v.z; d[3] = (__bf16)v.w;
    }

    // ---- one-time: Whh B-frags -> registers ----
    bf16x8 wR[16], wZ[16], wN[16];
    {
        const float* pR = Whh + (size_t)ch * HD;
        const float* pZ = Whh + (size_t)(HD + ch) * HD;
        const float* pN = Whh + (size_t)(2 * HD + ch) * HD;
        #pragma unroll
        for (int kk = 0; kk < 16; ++kk) {
            int ko = 32 * kk + kq8;
            wR[kk] = cvt8(pR + ko);
            wZ[kk] = cvt8(pZ + ko);
            wN[kk] = cvt8(pN + ko);
        }
    }
    const float bR  = bih[ch] + bhh[ch];
    const float bZ  = bih[HD + ch] + bhh[HD + ch];
    const float bNX = bih[2 * HD + ch];
    const float bNH = bhh[2 * HD + ch];

    const int xrow  = tid >> 4;
    const int xnode = nb + xrow;
    const int xcol  = (tid & 15) * 8;

    // ---- prologue: stage x_0, x-part MFMAs for t=0 ----
    {
        float4 xa = {0.f, 0.f, 0.f, 0.f}, xb = xa;
        if (xnode < NN) {
            const float* xp = x + (size_t)xnode * FD + xcol;
            xa = ((const float4*)xp)[0];
            xb = ((const float4*)xp)[1];
        }
        bf16x8 v;
        v[0] = (__bf16)xa.x; v[1] = (__bf16)xa.y; v[2] = (__bf16)xa.z; v[3] = (__bf16)xa.w;
        v[4] = (__bf16)xb.x; v[5] = (__bf16)xb.y; v[6] = (__bf16)xb.z; v[7] = (__bf16)xb.w;
        *(bf16x8*)(AxP + (size_t)xrow * WXST + xcol) = v;
    }
    __syncthreads();

    f32x4 accR = {0.f, 0.f, 0.f, 0.f}, accZ = accR, accNX = accR, accNH = accR;
    #pragma unroll
    for (int kk = 0; kk < 4; ++kk) {
        int ko = 32 * kk + kq8;
        bf16x8 av = *(const bf16x8*)(AxP + (size_t)mi * WXST + ko);
        accR  = MFMA16(av, *(const bf16x8*)(WxP + (size_t)cl * WXST + ko),         accR);
        accZ  = MFMA16(av, *(const bf16x8*)(WxP + (size_t)(64 + cl) * WXST + ko),  accZ);
        accNX = MFMA16(av, *(const bf16x8*)(WxP + (size_t)(128 + cl) * WXST + ko), accNX);
    }

    float hold[4] = {0.f, 0.f, 0.f, 0.f};

    const unsigned hv_voff = ((unsigned)(nb + mi) * HD + (unsigned)kq8) * 2u;
    const unsigned st_voff = ((unsigned)(nb + (ln >> 4) * 4) * HD + (unsigned)ch) * 2u;
    const unsigned tg_self = (unsigned)(g * NSL + s) * 64u;
    const unsigned tg_poll = (unsigned)(g * NSL + (ln & 7)) * 64u;

    #pragma unroll 1
    for (int t = 0; t < TS; ++t) {
        __bf16* hcur = (t & 1) ? h1buf : h0buf;
        __bf16* hnxt = (t & 1) ? h0buf : h1buf;

        // ---- prefetch x_{t+1} (plain cached loads; overlaps poll) ----
        float4 xa = {0.f, 0.f, 0.f, 0.f}, xb = xa;
        if (t + 1 < TS && xnode < NN) {
            const float* xp = x + ((size_t)(t + 1) * NN + xnode) * FD + xcol;
            xa = ((const float4*)xp)[0];
            xb = ((const float4*)xp)[1];
        }

        // ---- split poll: wait for producers 0-3, remember 4-7 bitmap ----
        unsigned rdy = 0;
        do {
            int v = tagload_a(tags, tg_poll);
            rdy = (unsigned)(__ballot(v >= t) & 0xFFull);
        } while ((rdy & 0x0Fu) != 0x0Fu);

        // ---- lower half: h k-cols [0,256) -> 8 frags, 24 MFMAs ----
        f32x4 hv0[8];
        loadh8_lo(hcur, hv_voff, hv0);
        #pragma unroll
        for (int kk = 0; kk < 8; ++kk) {
            bf16x8 av = __builtin_bit_cast(bf16x8, hv0[kk]);
            accR  = MFMA16(av, wR[kk], accR);
            accZ  = MFMA16(av, wZ[kk], accZ);
            accNH = MFMA16(av, wN[kk], accNH);
        }

        // ---- upper half: producers 4-7 (usually already seen ready) ----
        while ((rdy & 0xF0u) != 0xF0u) {
            int v = tagload_a(tags, tg_poll);
            rdy = (unsigned)(__ballot(v >= t) & 0xFFull);
        }
        f32x4 hv1[8];
        loadh8_hi(hcur, hv_voff, hv1);
        #pragma unroll
        for (int kk = 0; kk < 8; ++kk) {
            bf16x8 av = __builtin_bit_cast(bf16x8, hv1[kk]);
            accR  = MFMA16(av, wR[8 + kk], accR);
            accZ  = MFMA16(av, wZ[8 + kk], accZ);
            accNH = MFMA16(av, wN[8 + kk], accNH);
        }

        // ---- gates + h update (hold in regs) + direct publish ----
        unsigned pv[4];
        #pragma unroll
        for (int e = 0; e < 4; ++e) {
            float rv = sig_(accR[e] + bR);
            float zv = sig_(accZ[e] + bZ);
            float nv = tanh_(accNX[e] + bNX + rv * (accNH[e] + bNH));
            float hnew = (1.f - zv) * nv + zv * hold[e];
            hold[e] = hnew;
            pv[e] = (unsigned)__builtin_bit_cast(unsigned short, (__bf16)hnew);
        }
        storeh4_a(hnxt, st_voff, pv[0], pv[1], pv[2], pv[3]);
        asm volatile("s_waitcnt vmcnt(0)" ::: "memory");   // h stores acked at LLC
        __syncthreads();                                   // all waves acked
        if (tid == 0) tagstore_a(tags, tg_self, t + 1);

        // ---- slack window: stage x_{t+1}, run its x-part MFMAs ----
        const int nslot = (t + 1) & 1;
        if (t + 1 < TS) {
            bf16x8 v;
            v[0] = (__bf16)xa.x; v[1] = (__bf16)xa.y; v[2] = (__bf16)xa.z; v[3] = (__bf16)xa.w;
            v[4] = (__bf16)xb.x; v[5] = (__bf16)xb.y; v[6] = (__bf16)xb.z; v[7] = (__bf16)xb.w;
            *(bf16x8*)(AxP + ((size_t)nslot * 16 + xrow) * WXST + xcol) = v;
        }
        __syncthreads();

        accR = {0.f, 0.f, 0.f, 0.f}; accZ = accR; accNX = accR; accNH = accR;
        if (t + 1 < TS) {
            #pragma unroll
            for (int kk = 0; kk < 4; ++kk) {
                int ko = 32 * kk + kq8;
                bf16x8 av = *(const bf16x8*)(AxP + ((size_t)nslot * 16 + mi) * WXST + ko);
                accR  = MFMA16(av, *(const bf16x8*)(WxP + (size_t)cl * WXST + ko),         accR);
                accZ  = MFMA16(av, *(const bf16x8*)(WxP + (size_t)(64 + cl) * WXST + ko),  accZ);
                accNX = MFMA16(av, *(const bf16x8*)(WxP + (size_t)(128 + cl) * WXST + ko), accNX);
            }
        }
    }

    // ---- epilogue: final h -> enc (fp32) ----
    #pragma unroll
    for (int e = 0; e < 4; ++e) {
        int row = (ln >> 4) * 4 + e;
        if (nb + row < NN)
            enc[(size_t)(nb + row) * HD + ch] = hold[e];
    }
}

// sync layout (ints): [0..895] tags (56 slots, 64B-padded). Zero-initialized.
__global__ __launch_bounds__(256, 1) void gru_kernel(
    const float* __restrict__ x, const float* __restrict__ Wih,
    const float* __restrict__ Whh, const float* __restrict__ bih,
    const float* __restrict__ bhh,
    __bf16* h0buf, __bf16* h1buf, float* enc, int* sync)
{
    __shared__ __align__(16) __bf16 Wx[192 * WXST];
    __shared__ __align__(16) __bf16 Ax[2 * 16 * WXST];

    const int g = blockIdx.x >> 3;       // 0..6
    const int s = blockIdx.x & 7;        // 0..7

    gru_loop(x, Wih, Whh, bih, bhh, h0buf, h1buf, enc, sync, g, s, Wx, Ax);
}

// ===================== epilogue (tiny) =====================

__global__ void e1_gnn_in(const float* __restrict__ enc, const float* __restrict__ flat,
                          const float* __restrict__ emb, const float* __restrict__ fW,
                          const float* __restrict__ fb, float* __restrict__ gnn)
{
    int i = blockIdx.x, tid = threadIdx.x;
    const float4* src = (const float4*)(enc + (size_t)i * HD);
    float4* dst = (float4*)(gnn + (size_t)i * GIN);
    dst[tid] = src[tid];
    if (tid < 64) {
        float acc = fb[tid];
        const float* w  = fW + tid * 32;
        const float* fl = flat + i * 32;
        #pragma unroll
        for (int k = 0; k < 32; ++k) acc = fmaf(fl[k], w[k], acc);
        gnn[(size_t)i * GIN + HD + tid] = acc;
    }
    gnn[(size_t)i * GIN + HD + 64 + tid] = emb[(size_t)i * FD + tid];
}

__global__ void e2a_norm(const float* __restrict__ emb, float* __restrict__ mx)
{
    int j = threadIdx.x;
    if (j < NN) {
        float acc = 0.f;
        const float* e = emb + (size_t)j * FD;
        for (int d = 0; d < FD; ++d) acc = fmaf(e[d], e[d], acc);
        mx[j] = fmaxf(sqrtf(acc), 1e-8f);
    }
}

__global__ void e2b_knn(const float* __restrict__ emb, const float* __restrict__ mx,
                        int* __restrict__ tgt)
{
    int i = blockIdx.x, tid = threadIdx.x;   // 128 threads
    __shared__ float ei[FD];
    __shared__ float srow[NN];
    ei[tid] = emb[(size_t)i * FD + tid];
    __syncthreads();
    if (tid < NN) {
        float acc = 0.f;
        const float* e = emb + (size_t)tid * FD;
        for (int d = 0; d < FD; ++d) acc = fmaf(ei[d], e[d], acc);
        float sim = acc / (mx[i] * mx[tid]);
        srow[tid] = (tid == i) ? 0.f : sim;
    }
    __syncthreads();
    if (tid == 0) {
        for (int t = 0; t < KNN; ++t) {
            float best = -1e30f; int bi = 0;
            for (int j = 0; j < NN; ++j) { float v = srow[j]; if (v > best) { best = v; bi = j; } }
            srow[bi] = -1e30f;
            tgt[i * KNN + t] = bi;
        }
    }
}

__global__ void e3_agg(const float* __restrict__ xin, const int* __restrict__ tgt,
                       float* __restrict__ agg, float* __restrict__ cnt, int D)
{
    int e = blockIdx.x, src = e >> 3, tg = tgt[e];
    for (int d = threadIdx.x; d < D; d += blockDim.x)
        atomicAdd(&agg[(size_t)tg * D + d], xin[(size_t)src * D + d]);
    if (threadIdx.x == 0) atomicAdd(&cnt[tg], 1.0f);
}

__global__ void e4_sage(const float* __restrict__ agg, const float* __restrict__ xin,
                        const float* __restrict__ cnt,
                        const float* __restrict__ Wl, const float* __restrict__ Wr,
                        const float* __restrict__ b, float* __restrict__ out,
                        int Din, int Dout, int dorelu)
{
    int j = blockIdx.x, o = threadIdx.x;
    extern __shared__ float sm[];
    float* la = sm;
    float* lx = sm + Din;
    for (int d = o; d < Din; d += blockDim.x) {
        la[d] = agg[(size_t)j * Din + d];
        lx[d] = xin[(size_t)j * Din + d];
    }
    __syncthreads();
    float inv = 1.f / fmaxf(cnt[j], 1.f);
    float acc1 = 0.f, acc2 = 0.f;
    const float* wl = Wl + (size_t)o * Din;
    const float* wr = Wr + (size_t)o * Din;
    for (int k = 0; k < Din; ++k) {
        acc1 = fmaf(la[k], wl[k], acc1);
        acc2 = fmaf(lx[k], wr[k], acc2);
    }
    float v = fmaf(acc1, inv, acc2) + b[o];
    if (dorelu) v = fmaxf(v, 0.f);
    out[(size_t)j * Dout + o] = v;
}

__global__ void e7_out(const float* __restrict__ g, const float* __restrict__ enc,
                       const float* __restrict__ oW, const float* __restrict__ ob,
                       float* __restrict__ out)
{
    int j = threadIdx.x;
    if (j < NN) {
        float acc = ob[0];
        const float* gr = g + (size_t)j * GOUT;
        for (int d = 0; d < GOUT; ++d) acc = fmaf(gr[d], oW[d], acc);
        const float* er = enc + (size_t)j * HD;
        for (int d = 0; d < HD; ++d) acc = fmaf(er[d], oW[GOUT + d], acc);
        out[j] = 1.f / (1.f + expf(-acc));
    }
}

// ===================== launch =====================
extern "C" void kernel_launch(void* const* d_in, const int* in_sizes, int n_in,
                              void* d_out, int out_size, void* d_ws, size_t ws_size,
                              hipStream_t stream)
{
    const float* x    = (const float*)d_in[0];
    const float* flat = (const float*)d_in[1];
    const float* emb  = (const float*)d_in[2];
    const float* Wih  = (const float*)d_in[3];
    const float* Whh  = (const float*)d_in[4];
    const float* bih  = (const float*)d_in[5];
    const float* bhh  = (const float*)d_in[6];
    const float* fW   = (const float*)d_in[7];
    const float* fb   = (const float*)d_in[8];
    const float* s1Wl = (const float*)d_in[9];
    const float* s1Wr = (const float*)d_in[10];
    const float* s1b  = (const float*)d_in[11];
    const float* s2Wl = (const float*)d_in[12];
    const float* s2Wr = (const float*)d_in[13];
    const float* s2b  = (const float*)d_in[14];
    const float* oW   = (const float*)d_in[15];
    const float* ob   = (const float*)d_in[16];
    float* out = (float*)d_out;

    // workspace layout (bytes). Zero zone first -> single memset.
    char* p = (char*)d_ws;
    __bf16* h0buf = (__bf16*)(p + 0);        // 114688  [zero: h0]
    float*  agg1  = (float*)(p + 114688);    // 281600  [zero]
    float*  agg2  = (float*)(p + 396288);    // 102400  [zero]
    float*  cnt1  = (float*)(p + 498688);    // 448     [zero]
    float*  cnt2  = (float*)(p + 499136);    // 448     [zero]
    int*    sync  = (int*)  (p + 499584);    // 4608    [zero: tags]
    __bf16* h1buf = (__bf16*)(p + 504192);   // 114688
    float*  enc   = (float*)(p + 618880);    // 229376
    float*  gnn   = (float*)(p + 848256);    // 281600
    float*  h1s   = (float*)(p + 1129856);   // 102400
    float*  gbuf  = (float*)(p + 1232256);   // 51200
    float*  mx    = (float*)(p + 1283456);   // 448
    int*    tgt   = (int*)  (p + 1283904);   // 3200
    // total ~1.29 MiB

    (void)hipMemsetAsync(d_ws, 0, 504192, stream);

    gru_kernel<<<NG * NSL, 256, 0, stream>>>(x, Wih, Whh, bih, bhh, h0buf, h1buf, enc, sync);
    e1_gnn_in<<<NN, 128, 0, stream>>>(enc, flat, emb, fW, fb, gnn);
    e2a_norm<<<1, 128, 0, stream>>>(emb, mx);
    e2b_knn<<<NN, 128, 0, stream>>>(emb, mx, tgt);
    e3_agg<<<NN * KNN, 256, 0, stream>>>(gnn, tgt, agg1, cnt1, GIN);
    e4_sage<<<NN, GH, 2 * GIN * sizeof(float), stream>>>(agg1, gnn, cnt1, s1Wl, s1Wr, s1b, h1s, GIN, GH, 1);
    e3_agg<<<NN * KNN, 256, 0, stream>>>(h1s, tgt, agg2, cnt2, GH);
    e4_sage<<<NN, GOUT, 2 * GH * sizeof(float), stream>>>(agg2, h1s, cnt2, s2Wl, s2Wr, s2b, gbuf, GH, GOUT, 0);
    e7_out<<<1, 128, 0, stream>>>(gbuf, enc, oW, ob, out);
}